// Round 3
// 2665.360 us; speedup vs baseline: 1.1305x; 1.1305x over previous
//
#include <hip/hip_runtime.h>
#include <hip/hip_bf16.h>
#include <math.h>

// Problem constants
#define D_MODEL 1024
#define NHEAD   16
#define DKH     64
#define FFDIM   4096
#define NLAYER  6
#define BATCH   2
#define SEQ     2048
#define NTOK    (BATCH*SEQ)
#define QKVN    3072   // fused Q|K|V output width

typedef __bf16 bf16x8 __attribute__((ext_vector_type(8)));
typedef float  f32x4  __attribute__((ext_vector_type(4)));

static __device__ __forceinline__ float bf2f(unsigned short u) {
    union { unsigned int i; float f; } v; v.i = ((unsigned int)u) << 16; return v.f;
}
static __device__ __forceinline__ unsigned short f2bf(float f) {
    __hip_bfloat16 h = __float2bfloat16(f);
    return *reinterpret_cast<unsigned short*>(&h);
}

// async global->LDS, 16B per lane. LDS dest must be wave-uniform base;
// HW writes base + lane*16 (m104/m108). Global addr is per-lane.
static __device__ __forceinline__ void gld_lds16(const unsigned short* g, unsigned short* l)
{
    __builtin_amdgcn_global_load_lds(
        (const __attribute__((address_space(1))) void*)g,
        (__attribute__((address_space(3))) void*)l,
        16, 0, 0);
}

// -------------------- dtype detection --------------------
__global__ void detect_dtype(const unsigned int* __restrict__ p, int* __restrict__ flag)
{
    __shared__ int cnt;
    if (threadIdx.x == 0) cnt = 0;
    __syncthreads();
    int c = 0;
    for (int i = threadIdx.x; i < 1024; i += 256) {
        unsigned int e = (p[i] >> 7) & 0xFF;
        if (e >= 0x60 && e <= 0x90) c++;
    }
    atomicAdd(&cnt, c);
    __syncthreads();
    if (threadIdx.x == 0) *flag = (cnt < 512) ? 1 : 0;
}

// -------------------- bias/gain conversion into bf16 arena --------------------
// arena layout: [L][3072] fused qkv bias | bo [L][1024] | b1 [L][4096] | b2 | g1 | be1 | g2 | be2
__global__ __launch_bounds__(256) void cvt_params(
    const void* bq, const void* bk, const void* bv, const void* bo,
    const void* b1, const void* b2, const void* g1, const void* be1,
    const void* g2, const void* be2,
    unsigned short* __restrict__ arena, const int* __restrict__ flag)
{
    int i = blockIdx.x * 256 + threadIdx.x;
    if (i >= 79872) return;
    const void* src; int j;
    if (i < 18432) {
        int l = i / 3072, r = i - l * 3072;
        if (r < 1024)      { src = bq; j = l * 1024 + r; }
        else if (r < 2048) { src = bk; j = l * 1024 + r - 1024; }
        else               { src = bv; j = l * 1024 + r - 2048; }
    }
    else if (i < 24576) { src = bo;  j = i - 18432; }
    else if (i < 49152) { src = b1;  j = i - 24576; }
    else if (i < 55296) { src = b2;  j = i - 49152; }
    else if (i < 61440) { src = g1;  j = i - 55296; }
    else if (i < 67584) { src = be1; j = i - 61440; }
    else if (i < 73728) { src = g2;  j = i - 67584; }
    else                { src = be2; j = i - 73728; }
    arena[i] = (*flag) ? f2bf(((const float*)src)[j])
                       : ((const unsigned short*)src)[j];
}

// -------------------- embedding + positional encoding --------------------
__global__ __launch_bounds__(256) void embed_pe(const int* __restrict__ src,
        const void* __restrict__ emb,
        float* __restrict__ xf, unsigned short* __restrict__ xb,
        const int* __restrict__ flag)
{
    int tok = blockIdx.x;
    int b = tok / SEQ;
    int id = src[tok];
    int t = threadIdx.x;
    int d0 = t * 4;
    float ev[4];
    if (*flag) {
        float4 v = *(const float4*)((const float*)emb + (size_t)id * D_MODEL + d0);
        ev[0] = v.x; ev[1] = v.y; ev[2] = v.z; ev[3] = v.w;
    } else {
        ushort4 v = *(const ushort4*)((const unsigned short*)emb + (size_t)id * D_MODEL + d0);
        ev[0] = bf2f(v.x); ev[1] = bf2f(v.y); ev[2] = bf2f(v.z); ev[3] = bf2f(v.w);
    }
    float pos = (float)b;
    float vals[4];
    #pragma unroll
    for (int e = 0; e < 4; e++) {
        int d = d0 + e;
        int deven = d & ~1;
        float div_ = expf((float)deven * (-9.210340371976184f / 1024.0f));
        float ang = pos / div_;
        float pe = (d & 1) ? cosf(ang) : sinf(ang);
        vals[e] = ev[e] + pe;
    }
    float4 f4 = {vals[0], vals[1], vals[2], vals[3]};
    *(float4*)(xf + (size_t)tok * D_MODEL + d0) = f4;
    ushort4 o = {f2bf(vals[0]), f2bf(vals[1]), f2bf(vals[2]), f2bf(vals[3])};
    *(ushort4*)(xb + (size_t)tok * D_MODEL + d0) = o;
}

// -------------------- transpose (any dtype, +element offset) -> bf16 B^T ----
__global__ __launch_bounds__(256) void transpose_any(const void* __restrict__ in,
        size_t elemOff, unsigned short* __restrict__ out, int R, int Cn,
        const int* __restrict__ flag)
{
    __shared__ unsigned short tl[32][33];
    int isf = *flag;
    int c0 = blockIdx.x * 32, r0 = blockIdx.y * 32;
    int tc = threadIdx.x & 31, tr = threadIdx.x >> 5;
    #pragma unroll
    for (int i = 0; i < 4; i++) {
        int r = tr + i * 8;
        size_t idx = elemOff + (size_t)(r0 + r) * Cn + c0 + tc;
        tl[r][tc] = isf ? f2bf(((const float*)in)[idx])
                        : ((const unsigned short*)in)[idx];
    }
    __syncthreads();
    #pragma unroll
    for (int i = 0; i < 4; i++) {
        int r = tr + i * 8;
        out[(size_t)(c0 + r) * R + r0 + tc] = tl[tc][r];
    }
}

// -------------------- V transpose: qkv[:,2048:3072] -> vtb[B,H,64,S] --------
__global__ __launch_bounds__(256) void transpose_v(const unsigned short* __restrict__ qkv,
        unsigned short* __restrict__ vtb)
{
    __shared__ unsigned short tl[32][33];
    int s0 = blockIdx.x * 32, c0 = blockIdx.y * 32, b = blockIdx.z;
    int tc = threadIdx.x & 31, tr = threadIdx.x >> 5;
    #pragma unroll
    for (int i = 0; i < 4; i++) {
        int r = tr + i * 8;
        tl[r][tc] = qkv[(size_t)(b * SEQ + s0 + r) * QKVN + 2048 + c0 + tc];
    }
    __syncthreads();
    #pragma unroll
    for (int i = 0; i < 4; i++) {
        int r = tr + i * 8;        // r indexes d within this 32-col strip
        int dglob = c0 + r;
        int h = dglob >> 6, dd = dglob & 63;
        vtb[((size_t)(b * NHEAD + h) * DKH + dd) * SEQ + s0 + tc] = tl[tc][r];
    }
}

// -------------------- bf16 MFMA GEMM: C[M,N] = A[M,K] @ Bt^T + bias ---------
// m97 structure: linear LDS tiles, global_load_lds width=16 staging,
// double-buffered 2-phase (stage k+1 while computing k; one vmcnt-drain
// barrier per K-step -> latency hidden even at 1 block/CU).
template<int RELU>
__global__ __launch_bounds__(256) void gemm_bt(
        const unsigned short* __restrict__ A,
        const unsigned short* __restrict__ Bt,
        const unsigned short* __restrict__ bias,
        unsigned short* __restrict__ C,
        int M, int N, int K)
{
    __shared__ unsigned short As[2][128][32];
    __shared__ unsigned short Bs[2][128][32];
    int tid = threadIdx.x;
    int lane = tid & 63;
    int wave = tid >> 6;
    int bm = blockIdx.x * 128;
    int bn = blockIdx.y * 128;
    int wm = (wave >> 1) * 64;
    int wn = (wave & 1) * 64;
    int l15 = lane & 15;
    int quad = lane >> 4;

    f32x4 acc[4][4] = {};

    // staging: 8 chunks of 1024B per matrix tile; wave w owns chunks 2w,2w+1.
    // chunk ch covers rows [ch*16, ch*16+16); lane l -> row ch*16 + l/4, col (l&3)*8.
    int srow = lane >> 2;
    int scol = (lane & 3) * 8;
    int c0 = wave * 2, c1 = wave * 2 + 1;
    const unsigned short* Ag0 = A  + (size_t)(bm + c0 * 16 + srow) * K + scol;
    const unsigned short* Ag1 = A  + (size_t)(bm + c1 * 16 + srow) * K + scol;
    const unsigned short* Bg0 = Bt + (size_t)(bn + c0 * 16 + srow) * K + scol;
    const unsigned short* Bg1 = Bt + (size_t)(bn + c1 * 16 + srow) * K + scol;

#define GSTAGE(BUF, KOFF) do { \
    gld_lds16(Ag0 + (KOFF), &As[BUF][c0 * 16][0]); \
    gld_lds16(Ag1 + (KOFF), &As[BUF][c1 * 16][0]); \
    gld_lds16(Bg0 + (KOFF), &Bs[BUF][c0 * 16][0]); \
    gld_lds16(Bg1 + (KOFF), &Bs[BUF][c1 * 16][0]); \
} while (0)

#define GCOMPUTE(BUF) do { \
    bf16x8 af[4], bfr[4]; \
    _Pragma("unroll") \
    for (int i = 0; i < 4; i++) af[i] = *(const bf16x8*)&As[BUF][wm + i * 16 + l15][quad * 8]; \
    _Pragma("unroll") \
    for (int j = 0; j < 4; j++) bfr[j] = *(const bf16x8*)&Bs[BUF][wn + j * 16 + l15][quad * 8]; \
    _Pragma("unroll") \
    for (int i = 0; i < 4; i++) { \
        _Pragma("unroll") \
        for (int j = 0; j < 4; j++) \
            acc[i][j] = __builtin_amdgcn_mfma_f32_16x16x32_bf16(af[i], bfr[j], acc[i][j], 0, 0, 0); \
    } \
} while (0)

    GSTAGE(0, 0);
    __syncthreads();              // compiler emits vmcnt(0) drain before barrier
    int cur = 0;
    for (int k0 = 32; k0 < K; k0 += 32) {
        GSTAGE(cur ^ 1, k0);      // async prefetch of next tile, in flight during compute
        GCOMPUTE(cur);
        __syncthreads();          // drains prefetch + guards buffer reuse
        cur ^= 1;
    }
    GCOMPUTE(cur);

#undef GSTAGE
#undef GCOMPUTE

    #pragma unroll
    for (int i = 0; i < 4; i++) {
        int row0 = bm + wm + i * 16 + quad * 4;
        #pragma unroll
        for (int j = 0; j < 4; j++) {
            int col = bn + wn + j * 16 + l15;
            float bv = bf2f(bias[col]);
            #pragma unroll
            for (int r = 0; r < 4; r++) {
                float v = acc[i][j][r] + bv;
                if (RELU) v = fmaxf(v, 0.0f);
                C[(size_t)(row0 + r) * N + col] = f2bf(v);
            }
        }
    }
}

// -------------------- MFMA flash attention --------------------
// Block: 256 thr (4 waves), Q-tile 128 (32 q/wave), K-tile 64, head dim 64.
// q/k read from fused qkv buffer (row stride 3072, k at +1024).
// scale = 1/sqrt(D_MODEL) = 1/32 (reference quirk).
__global__ __launch_bounds__(256) void attn_mfma(
        const unsigned short* __restrict__ qkv,
        const unsigned short* __restrict__ vtb,   // [B,H,64,SEQ]
        const int* __restrict__ mask,
        unsigned short* __restrict__ out)
{
    __shared__ unsigned short Ks[64][72];
    __shared__ unsigned short Vt[64][72];
    __shared__ unsigned short Ps[128][72];

    int qt = blockIdx.x, h = blockIdx.y, b = blockIdx.z;
    int t = threadIdx.x, lane = t & 63, wave = t >> 6;
    int l15 = lane & 15, quad = lane >> 4;
    int q0 = qt * 128;
    int wq = wave * 32;

    const unsigned short* qbase = qkv + (size_t)b * SEQ * QKVN + h * DKH;
    const unsigned short* kbase_p = qkv + (size_t)b * SEQ * QKVN + 1024 + h * DKH;
    const unsigned short* vbase_p = vtb + (size_t)(b * NHEAD + h) * DKH * SEQ;

    // Q fragments: 2 m-tiles x 2 k-chunks, resident all kernel
    bf16x8 qf[2][2];
    #pragma unroll
    for (int im = 0; im < 2; im++)
        #pragma unroll
        for (int kc = 0; kc < 2; kc++)
            qf[im][kc] = *(const bf16x8*)(qbase +
                (size_t)(q0 + wq + im * 16 + l15) * QKVN + kc * 32 + quad * 8);

    f32x4 oacc[2][4] = {};
    float mrow[2][4], lrow[2][4];
    #pragma unroll
    for (int im = 0; im < 2; im++)
        #pragma unroll
        for (int r = 0; r < 4; r++) { mrow[im][r] = -INFINITY; lrow[im][r] = 0.0f; }

    for (int kb = 0; kb < SEQ; kb += 64) {
        // stage K tile (rows: key, cols: d) and Vt tile (rows: d, cols: key)
        #pragma unroll
        for (int c = t; c < 512; c += 256) {
            int r = c >> 3, o = (c & 7) * 8;
            *(int4*)&Ks[r][o] = *(const int4*)(kbase_p + (size_t)(kb + r) * QKVN + o);
            *(int4*)&Vt[r][o] = *(const int4*)(vbase_p + (size_t)r * SEQ + kb + o);
        }
        __syncthreads();

        #pragma unroll
        for (int im = 0; im < 2; im++) {
            // scores: 16q x 64k strip
            f32x4 s[4];
            #pragma unroll
            for (int jn = 0; jn < 4; jn++) {
                f32x4 a = {0.f, 0.f, 0.f, 0.f};
                #pragma unroll
                for (int kc = 0; kc < 2; kc++) {
                    bf16x8 kf = *(const bf16x8*)&Ks[jn * 16 + l15][kc * 32 + quad * 8];
                    a = __builtin_amdgcn_mfma_f32_16x16x32_bf16(qf[im][kc], kf, a, 0, 0, 0);
                }
                int mv = mask[b * SEQ + kb + jn * 16 + l15];
                #pragma unroll
                for (int r = 0; r < 4; r++)
                    a[r] = mv ? a[r] * (1.0f / 32.0f) : -1e9f;
                s[jn] = a;
            }
            // row max (local over jn, then across 16 cols in quad group)
            f32x4 mx = s[0];
            #pragma unroll
            for (int jn = 1; jn < 4; jn++)
                #pragma unroll
                for (int r = 0; r < 4; r++) mx[r] = fmaxf(mx[r], s[jn][r]);
            #pragma unroll
            for (int d = 1; d < 16; d <<= 1)
                #pragma unroll
                for (int r = 0; r < 4; r++)
                    mx[r] = fmaxf(mx[r], __shfl_xor(mx[r], d, 16));
            float alpha[4], mnew[4];
            #pragma unroll
            for (int r = 0; r < 4; r++) {
                mnew[r] = fmaxf(mrow[im][r], mx[r]);
                alpha[r] = __expf(mrow[im][r] - mnew[r]);
                mrow[im][r] = mnew[r];
            }
            // p = exp(s - mnew), row sums, write P to LDS
            f32x4 sum = {0.f, 0.f, 0.f, 0.f};
            #pragma unroll
            for (int jn = 0; jn < 4; jn++) {
                #pragma unroll
                for (int r = 0; r < 4; r++) {
                    float p = __expf(s[jn][r] - mnew[r]);
                    sum[r] += p;
                    Ps[wq + im * 16 + quad * 4 + r][jn * 16 + l15] = f2bf(p);
                }
            }
            #pragma unroll
            for (int d = 1; d < 16; d <<= 1)
                #pragma unroll
                for (int r = 0; r < 4; r++)
                    sum[r] += __shfl_xor(sum[r], d, 16);
            #pragma unroll
            for (int r = 0; r < 4; r++)
                lrow[im][r] = lrow[im][r] * alpha[r] + sum[r];
            // rescale O accumulators
            #pragma unroll
            for (int jd = 0; jd < 4; jd++)
                #pragma unroll
                for (int r = 0; r < 4; r++)
                    oacc[im][jd][r] *= alpha[r];
        }
        __syncthreads();
        // O += P @ V
        #pragma unroll
        for (int im = 0; im < 2; im++)
            #pragma unroll
            for (int jd = 0; jd < 4; jd++)
                #pragma unroll
                for (int kc = 0; kc < 2; kc++) {
                    bf16x8 pf = *(const bf16x8*)&Ps[wq + im * 16 + l15][kc * 32 + quad * 8];
                    bf16x8 vf = *(const bf16x8*)&Vt[jd * 16 + l15][kc * 32 + quad * 8];
                    oacc[im][jd] = __builtin_amdgcn_mfma_f32_16x16x32_bf16(pf, vf, oacc[im][jd], 0, 0, 0);
                }
        __syncthreads();
    }

    // epilogue: O / l
    #pragma unroll
    for (int im = 0; im < 2; im++) {
        float inv[4];
        #pragma unroll
        for (int r = 0; r < 4; r++) inv[r] = 1.0f / lrow[im][r];
        #pragma unroll
        for (int jd = 0; jd < 4; jd++) {
            #pragma unroll
            for (int r = 0; r < 4; r++) {
                int row = b * SEQ + q0 + wq + im * 16 + quad * 4 + r;
                int col = h * DKH + jd * 16 + l15;
                out[(size_t)row * D_MODEL + col] = f2bf(oacc[im][jd][r] * inv[r]);
            }
        }
    }
}

// -------------------- fused residual add + LayerNorm --------------------
__global__ __launch_bounds__(256) void add_ln(
        float* __restrict__ xf,
        const unsigned short* __restrict__ delta,
        const unsigned short* __restrict__ g,
        const unsigned short* __restrict__ be,
        unsigned short* __restrict__ xb)
{
    __shared__ float wsum[4], wsum2[4];
    int tok = blockIdx.x;
    int t = threadIdx.x;
    int d0 = t * 4;
    float4 xv = *(float4*)(xf + (size_t)tok * D_MODEL + d0);
    ushort4 dv = *(const ushort4*)(delta + (size_t)tok * D_MODEL + d0);
    float v0 = xv.x + bf2f(dv.x);
    float v1 = xv.y + bf2f(dv.y);
    float v2 = xv.z + bf2f(dv.z);
    float v3 = xv.w + bf2f(dv.w);
    float s = v0 + v1 + v2 + v3;
    float s2 = v0 * v0 + v1 * v1 + v2 * v2 + v3 * v3;
    #pragma unroll
    for (int off = 32; off > 0; off >>= 1) {
        s  += __shfl_down(s, off);
        s2 += __shfl_down(s2, off);
    }
    int wave = t >> 6, lane = t & 63;
    if (lane == 0) { wsum[wave] = s; wsum2[wave] = s2; }
    __syncthreads();
    float tot  = wsum[0] + wsum[1] + wsum[2] + wsum[3];
    float tot2 = wsum2[0] + wsum2[1] + wsum2[2] + wsum2[3];
    float mean = tot * (1.0f / 1024.0f);
    float var  = tot2 * (1.0f / 1024.0f) - mean * mean;
    float rs = rsqrtf(var + 1e-5f);
    ushort4 gv  = *(const ushort4*)(g + d0);
    ushort4 bev = *(const ushort4*)(be + d0);
    float y0 = (v0 - mean) * rs * bf2f(gv.x) + bf2f(bev.x);
    float y1 = (v1 - mean) * rs * bf2f(gv.y) + bf2f(bev.y);
    float y2 = (v2 - mean) * rs * bf2f(gv.z) + bf2f(bev.z);
    float y3 = (v3 - mean) * rs * bf2f(gv.w) + bf2f(bev.w);
    float4 yo = {y0, y1, y2, y3};
    *(float4*)(xf + (size_t)tok * D_MODEL + d0) = yo;
    ushort4 ob = {f2bf(y0), f2bf(y1), f2bf(y2), f2bf(y3)};
    *(ushort4*)(xb + (size_t)tok * D_MODEL + d0) = ob;
}

// -------------------- output store (dtype per flag) --------------------
__global__ __launch_bounds__(256) void copy_out_any(const float* __restrict__ xf,
        void* __restrict__ out, const int* __restrict__ flag)
{
    int i = blockIdx.x * 1024 + threadIdx.x * 4;
    float4 vv = *(const float4*)(xf + i);
    if (*flag) {
        *(float4*)((float*)out + i) = vv;
    } else {
        ushort4 o = {f2bf(vv.x), f2bf(vv.y), f2bf(vv.z), f2bf(vv.w)};
        *(ushort4*)((unsigned short*)out + i) = o;
    }
}

// -------------------- host side --------------------
extern "C" void kernel_launch(void* const* d_in, const int* in_sizes, int n_in,
                              void* d_out, int out_size, void* d_ws, size_t ws_size,
                              hipStream_t stream)
{
    const int* src  = (const int*)d_in[0];
    const int* mask = (const int*)d_in[1];
    const void* emb = d_in[2];
    const void* Wq  = d_in[3];
    const void* bq  = d_in[4];
    const void* Wk  = d_in[5];
    const void* bk  = d_in[6];
    const void* Wv  = d_in[7];
    const void* bv  = d_in[8];
    const void* Wo  = d_in[9];
    const void* bo  = d_in[10];
    const void* W1  = d_in[11];
    const void* b1  = d_in[12];
    const void* W2  = d_in[13];
    const void* b2  = d_in[14];
    const void* g1  = d_in[15];
    const void* be1 = d_in[16];
    const void* g2  = d_in[17];
    const void* be2 = d_in[18];

    char* wsb = (char*)d_ws;
    size_t off = 0;
    auto alloc = [&](size_t bytes) -> void* {
        void* p = wsb + off;
        off += (bytes + 255) & ~(size_t)255;
        return p;
    };
    float* xf           = (float*)alloc((size_t)NTOK * D_MODEL * 4);
    unsigned short* xb  = (unsigned short*)alloc((size_t)NTOK * D_MODEL * 2);
    unsigned short* qkv = (unsigned short*)alloc((size_t)NTOK * QKVN * 2);
    unsigned short* ao  = (unsigned short*)alloc((size_t)NTOK * D_MODEL * 2);
    unsigned short* ffb = (unsigned short*)alloc((size_t)NTOK * FFDIM * 2);
    unsigned short* wT  = (unsigned short*)alloc((size_t)D_MODEL * FFDIM * 2);
    unsigned short* arena = (unsigned short*)alloc(79872 * 2);
    int* flag           = (int*)alloc(256);
    unsigned short* tmp = qkv;   // qkv dead after attention; reuse for deltas
    unsigned short* vtb = ffb;   // ffb dead during attention; holds V^T [B,H,64,S]
    (void)ws_size; (void)in_sizes; (void)n_in; (void)out_size;

    const unsigned short* c_bqkv = arena;              // [L][3072]
    const unsigned short* c_bo  = arena + 18432;
    const unsigned short* c_b1  = arena + 24576;
    const unsigned short* c_b2  = arena + 49152;
    const unsigned short* c_g1  = arena + 55296;
    const unsigned short* c_be1 = arena + 61440;
    const unsigned short* c_g2  = arena + 67584;
    const unsigned short* c_be2 = arena + 73728;

    detect_dtype<<<1, 256, 0, stream>>>((const unsigned int*)emb, flag);
    cvt_params<<<312, 256, 0, stream>>>(bq, bk, bv, bo, b1, b2, g1, be1, g2, be2, arena, flag);
    embed_pe<<<NTOK, 256, 0, stream>>>(src, emb, xf, xb, flag);

    for (int l = 0; l < NLAYER; l++) {
        size_t offDD = (size_t)l * D_MODEL * D_MODEL;
        size_t offDF = (size_t)l * D_MODEL * FFDIM;

        // fused QKV: wT = [Wq^T | Wk^T | Wv^T] (3072 x 1024), one 768-block GEMM
        transpose_any<<<dim3(32, 32), 256, 0, stream>>>(Wq, offDD, wT,           D_MODEL, D_MODEL, flag);
        transpose_any<<<dim3(32, 32), 256, 0, stream>>>(Wk, offDD, wT + 1048576, D_MODEL, D_MODEL, flag);
        transpose_any<<<dim3(32, 32), 256, 0, stream>>>(Wv, offDD, wT + 2097152, D_MODEL, D_MODEL, flag);
        gemm_bt<0><<<dim3(32, 24), 256, 0, stream>>>(xb, wT, c_bqkv + (size_t)l * QKVN, qkv,
                                                     NTOK, QKVN, D_MODEL);

        transpose_v<<<dim3(SEQ / 32, D_MODEL / 32, BATCH), 256, 0, stream>>>(qkv, vtb);
        attn_mfma<<<dim3(SEQ / 128, NHEAD, BATCH), 256, 0, stream>>>(qkv, vtb, mask, ao);

        transpose_any<<<dim3(32, 32), 256, 0, stream>>>(Wo, offDD, wT, D_MODEL, D_MODEL, flag);
        gemm_bt<0><<<dim3(32, 8), 256, 0, stream>>>(ao, wT, c_bo + (size_t)l * D_MODEL, tmp,
                                                    NTOK, D_MODEL, D_MODEL);
        add_ln<<<NTOK, 256, 0, stream>>>(xf, tmp, c_g1 + (size_t)l * D_MODEL, c_be1 + (size_t)l * D_MODEL, xb);

        transpose_any<<<dim3(128, 32), 256, 0, stream>>>(W1, offDF, wT, D_MODEL, FFDIM, flag);
        gemm_bt<1><<<dim3(32, 32), 256, 0, stream>>>(xb, wT, c_b1 + (size_t)l * FFDIM, ffb,
                                                     NTOK, FFDIM, D_MODEL);
        transpose_any<<<dim3(32, 128), 256, 0, stream>>>(W2, offDF, wT, FFDIM, D_MODEL, flag);
        gemm_bt<0><<<dim3(32, 8), 256, 0, stream>>>(ffb, wT, c_b2 + (size_t)l * D_MODEL, tmp,
                                                    NTOK, D_MODEL, FFDIM);
        add_ln<<<NTOK, 256, 0, stream>>>(xf, tmp, c_g2 + (size_t)l * D_MODEL, c_be2 + (size_t)l * D_MODEL, xb);
    }

    copy_out_any<<<NTOK, 256, 0, stream>>>(xf, d_out, flag);
}

// Round 4
// 2631.980 us; speedup vs baseline: 1.1448x; 1.0127x over previous
//
#include <hip/hip_runtime.h>
#include <hip/hip_bf16.h>
#include <math.h>

// Problem constants
#define D_MODEL 1024
#define NHEAD   16
#define DKH     64
#define FFDIM   4096
#define NLAYER  6
#define BATCH   2
#define SEQ     2048
#define NTOK    (BATCH*SEQ)
#define QKVN    3072   // fused Q|K|V output width

typedef __bf16 bf16x8 __attribute__((ext_vector_type(8)));
typedef float  f32x4  __attribute__((ext_vector_type(4)));

static __device__ __forceinline__ float bf2f(unsigned short u) {
    union { unsigned int i; float f; } v; v.i = ((unsigned int)u) << 16; return v.f;
}
static __device__ __forceinline__ unsigned short f2bf(float f) {
    __hip_bfloat16 h = __float2bfloat16(f);
    return *reinterpret_cast<unsigned short*>(&h);
}

// async global->LDS, 16B per lane. LDS dest must be wave-uniform base;
// HW writes base + lane*16 (m104/m108). Global addr is per-lane.
static __device__ __forceinline__ void gld_lds16(const unsigned short* g, unsigned short* l)
{
    __builtin_amdgcn_global_load_lds(
        (const __attribute__((address_space(1))) void*)g,
        (__attribute__((address_space(3))) void*)l,
        16, 0, 0);
}

// -------------------- dtype detection --------------------
__global__ void detect_dtype(const unsigned int* __restrict__ p, int* __restrict__ flag)
{
    __shared__ int cnt;
    if (threadIdx.x == 0) cnt = 0;
    __syncthreads();
    int c = 0;
    for (int i = threadIdx.x; i < 1024; i += 256) {
        unsigned int e = (p[i] >> 7) & 0xFF;
        if (e >= 0x60 && e <= 0x90) c++;
    }
    atomicAdd(&cnt, c);
    __syncthreads();
    if (threadIdx.x == 0) *flag = (cnt < 512) ? 1 : 0;
}

// -------------------- bias/gain conversion into bf16 arena --------------------
// arena layout: [L][3072] fused qkv bias | bo [L][1024] | b1 [L][4096] | b2 | g1 | be1 | g2 | be2
__global__ __launch_bounds__(256) void cvt_params(
    const void* bq, const void* bk, const void* bv, const void* bo,
    const void* b1, const void* b2, const void* g1, const void* be1,
    const void* g2, const void* be2,
    unsigned short* __restrict__ arena, const int* __restrict__ flag)
{
    int i = blockIdx.x * 256 + threadIdx.x;
    if (i >= 79872) return;
    const void* src; int j;
    if (i < 18432) {
        int l = i / 3072, r = i - l * 3072;
        if (r < 1024)      { src = bq; j = l * 1024 + r; }
        else if (r < 2048) { src = bk; j = l * 1024 + r - 1024; }
        else               { src = bv; j = l * 1024 + r - 2048; }
    }
    else if (i < 24576) { src = bo;  j = i - 18432; }
    else if (i < 49152) { src = b1;  j = i - 24576; }
    else if (i < 55296) { src = b2;  j = i - 49152; }
    else if (i < 61440) { src = g1;  j = i - 55296; }
    else if (i < 67584) { src = be1; j = i - 61440; }
    else if (i < 73728) { src = g2;  j = i - 67584; }
    else                { src = be2; j = i - 73728; }
    arena[i] = (*flag) ? f2bf(((const float*)src)[j])
                       : ((const unsigned short*)src)[j];
}

// -------------------- embedding + positional encoding --------------------
__global__ __launch_bounds__(256) void embed_pe(const int* __restrict__ src,
        const void* __restrict__ emb,
        float* __restrict__ xf, unsigned short* __restrict__ xb,
        const int* __restrict__ flag)
{
    int tok = blockIdx.x;
    int b = tok / SEQ;
    int id = src[tok];
    int t = threadIdx.x;
    int d0 = t * 4;
    float ev[4];
    if (*flag) {
        float4 v = *(const float4*)((const float*)emb + (size_t)id * D_MODEL + d0);
        ev[0] = v.x; ev[1] = v.y; ev[2] = v.z; ev[3] = v.w;
    } else {
        ushort4 v = *(const ushort4*)((const unsigned short*)emb + (size_t)id * D_MODEL + d0);
        ev[0] = bf2f(v.x); ev[1] = bf2f(v.y); ev[2] = bf2f(v.z); ev[3] = bf2f(v.w);
    }
    float pos = (float)b;
    float vals[4];
    #pragma unroll
    for (int e = 0; e < 4; e++) {
        int d = d0 + e;
        int deven = d & ~1;
        float div_ = expf((float)deven * (-9.210340371976184f / 1024.0f));
        float ang = pos / div_;
        float pe = (d & 1) ? cosf(ang) : sinf(ang);
        vals[e] = ev[e] + pe;
    }
    float4 f4 = {vals[0], vals[1], vals[2], vals[3]};
    *(float4*)(xf + (size_t)tok * D_MODEL + d0) = f4;
    ushort4 o = {f2bf(vals[0]), f2bf(vals[1]), f2bf(vals[2]), f2bf(vals[3])};
    *(ushort4*)(xb + (size_t)tok * D_MODEL + d0) = o;
}

// -------------------- transpose (any dtype, +element offset) -> bf16 B^T ----
__global__ __launch_bounds__(256) void transpose_any(const void* __restrict__ in,
        size_t elemOff, unsigned short* __restrict__ out, int R, int Cn,
        const int* __restrict__ flag)
{
    __shared__ unsigned short tl[32][33];
    int isf = *flag;
    int c0 = blockIdx.x * 32, r0 = blockIdx.y * 32;
    int tc = threadIdx.x & 31, tr = threadIdx.x >> 5;
    #pragma unroll
    for (int i = 0; i < 4; i++) {
        int r = tr + i * 8;
        size_t idx = elemOff + (size_t)(r0 + r) * Cn + c0 + tc;
        tl[r][tc] = isf ? f2bf(((const float*)in)[idx])
                        : ((const unsigned short*)in)[idx];
    }
    __syncthreads();
    #pragma unroll
    for (int i = 0; i < 4; i++) {
        int r = tr + i * 8;
        out[(size_t)(c0 + r) * R + r0 + tc] = tl[tc][r];
    }
}

// -------------------- V transpose: qkv[:,2048:3072] -> vtb[B,H,64,S] --------
__global__ __launch_bounds__(256) void transpose_v(const unsigned short* __restrict__ qkv,
        unsigned short* __restrict__ vtb)
{
    __shared__ unsigned short tl[32][33];
    int s0 = blockIdx.x * 32, c0 = blockIdx.y * 32, b = blockIdx.z;
    int tc = threadIdx.x & 31, tr = threadIdx.x >> 5;
    #pragma unroll
    for (int i = 0; i < 4; i++) {
        int r = tr + i * 8;
        tl[r][tc] = qkv[(size_t)(b * SEQ + s0 + r) * QKVN + 2048 + c0 + tc];
    }
    __syncthreads();
    #pragma unroll
    for (int i = 0; i < 4; i++) {
        int r = tr + i * 8;        // r indexes d within this 32-col strip
        int dglob = c0 + r;
        int h = dglob >> 6, dd = dglob & 63;
        vtb[((size_t)(b * NHEAD + h) * DKH + dd) * SEQ + s0 + tc] = tl[tc][r];
    }
}

// -------------------- bf16 MFMA GEMM: C[M,N] = A[M,K] @ Bt^T + bias ---------
// m97 structure: linear LDS tiles, global_load_lds width=16 staging,
// double-buffered 2-phase (stage k+1 while computing k; one vmcnt-drain
// barrier per K-step -> latency hidden even at 1 block/CU).
template<int RELU>
__global__ __launch_bounds__(256) void gemm_bt(
        const unsigned short* __restrict__ A,
        const unsigned short* __restrict__ Bt,
        const unsigned short* __restrict__ bias,
        unsigned short* __restrict__ C,
        int M, int N, int K)
{
    __shared__ unsigned short As[2][128][32];
    __shared__ unsigned short Bs[2][128][32];
    int tid = threadIdx.x;
    int lane = tid & 63;
    int wave = tid >> 6;
    int bm = blockIdx.x * 128;
    int bn = blockIdx.y * 128;
    int wm = (wave >> 1) * 64;
    int wn = (wave & 1) * 64;
    int l15 = lane & 15;
    int quad = lane >> 4;

    f32x4 acc[4][4] = {};

    // staging: 8 chunks of 1024B per matrix tile; wave w owns chunks 2w,2w+1.
    // chunk ch covers rows [ch*16, ch*16+16); lane l -> row ch*16 + l/4, col (l&3)*8.
    int srow = lane >> 2;
    int scol = (lane & 3) * 8;
    int c0 = wave * 2, c1 = wave * 2 + 1;
    const unsigned short* Ag0 = A  + (size_t)(bm + c0 * 16 + srow) * K + scol;
    const unsigned short* Ag1 = A  + (size_t)(bm + c1 * 16 + srow) * K + scol;
    const unsigned short* Bg0 = Bt + (size_t)(bn + c0 * 16 + srow) * K + scol;
    const unsigned short* Bg1 = Bt + (size_t)(bn + c1 * 16 + srow) * K + scol;

#define GSTAGE(BUF, KOFF) do { \
    gld_lds16(Ag0 + (KOFF), &As[BUF][c0 * 16][0]); \
    gld_lds16(Ag1 + (KOFF), &As[BUF][c1 * 16][0]); \
    gld_lds16(Bg0 + (KOFF), &Bs[BUF][c0 * 16][0]); \
    gld_lds16(Bg1 + (KOFF), &Bs[BUF][c1 * 16][0]); \
} while (0)

#define GCOMPUTE(BUF) do { \
    bf16x8 af[4], bfr[4]; \
    _Pragma("unroll") \
    for (int i = 0; i < 4; i++) af[i] = *(const bf16x8*)&As[BUF][wm + i * 16 + l15][quad * 8]; \
    _Pragma("unroll") \
    for (int j = 0; j < 4; j++) bfr[j] = *(const bf16x8*)&Bs[BUF][wn + j * 16 + l15][quad * 8]; \
    _Pragma("unroll") \
    for (int i = 0; i < 4; i++) { \
        _Pragma("unroll") \
        for (int j = 0; j < 4; j++) \
            acc[i][j] = __builtin_amdgcn_mfma_f32_16x16x32_bf16(af[i], bfr[j], acc[i][j], 0, 0, 0); \
    } \
} while (0)

    GSTAGE(0, 0);
    __syncthreads();              // compiler emits vmcnt(0) drain before barrier
    int cur = 0;
    for (int k0 = 32; k0 < K; k0 += 32) {
        GSTAGE(cur ^ 1, k0);      // async prefetch of next tile, in flight during compute
        GCOMPUTE(cur);
        __syncthreads();          // drains prefetch + guards buffer reuse
        cur ^= 1;
    }
    GCOMPUTE(cur);

#undef GSTAGE
#undef GCOMPUTE

    #pragma unroll
    for (int i = 0; i < 4; i++) {
        int row0 = bm + wm + i * 16 + quad * 4;
        #pragma unroll
        for (int j = 0; j < 4; j++) {
            int col = bn + wn + j * 16 + l15;
            float bv = bf2f(bias[col]);
            #pragma unroll
            for (int r = 0; r < 4; r++) {
                float v = acc[i][j][r] + bv;
                if (RELU) v = fmaxf(v, 0.0f);
                C[(size_t)(row0 + r) * N + col] = f2bf(v);
            }
        }
    }
}

// -------------------- MFMA flash attention --------------------
// Block: 512 thr (8 waves), Q-tile 128 (16 q/wave), K-tile 64, head dim 64.
// 512 blocks x 8 waves -> 16 waves/CU (50% occupancy) vs old 4-wave/256-thr
// version (25% cap, measured 21.6%): more TLP to hide softmax/LDS latency.
// q/k read from fused qkv buffer (row stride 3072, k at +1024).
// Exact defer-max: when no row's tile-max exceeds the running max, alpha==1
// identically -> skip alpha exp + O/l rescale (wave-uniform branch, no barrier).
// scale = 1/sqrt(D_MODEL) = 1/32 (reference quirk).
__global__ __launch_bounds__(512) void attn_mfma(
        const unsigned short* __restrict__ qkv,
        const unsigned short* __restrict__ vtb,   // [B,H,64,SEQ]
        const int* __restrict__ mask,
        unsigned short* __restrict__ out)
{
    __shared__ unsigned short Ks[64][72];
    __shared__ unsigned short Vt[64][72];
    __shared__ unsigned short Ps[128][72];

    int qt = blockIdx.x, h = blockIdx.y, b = blockIdx.z;
    int t = threadIdx.x, lane = t & 63, wave = t >> 6;   // 8 waves
    int l15 = lane & 15, quad = lane >> 4;
    int q0 = qt * 128;
    int wq = wave * 16;                                   // 16 q rows per wave

    const unsigned short* qbase   = qkv + (size_t)b * SEQ * QKVN + h * DKH;
    const unsigned short* kbase_p = qkv + (size_t)b * SEQ * QKVN + 1024 + h * DKH;
    const unsigned short* vbase_p = vtb + (size_t)(b * NHEAD + h) * DKH * SEQ;

    // Q fragments: 2 k-chunks, resident all kernel
    bf16x8 qf[2];
    #pragma unroll
    for (int kc = 0; kc < 2; kc++)
        qf[kc] = *(const bf16x8*)(qbase +
            (size_t)(q0 + wq + l15) * QKVN + kc * 32 + quad * 8);

    f32x4 oacc[4] = {};
    float mrow[4], lrow[4];
    #pragma unroll
    for (int r = 0; r < 4; r++) { mrow[r] = -INFINITY; lrow[r] = 0.0f; }

    // staging coords: 512 threads, one int4 each; row = t/8, col = (t%8)*8
    int sr = t >> 3, so = (t & 7) * 8;

    for (int kb = 0; kb < SEQ; kb += 64) {
        // stage K tile (rows: key, cols: d) and Vt tile (rows: d, cols: key)
        *(int4*)&Ks[sr][so] = *(const int4*)(kbase_p + (size_t)(kb + sr) * QKVN + so);
        *(int4*)&Vt[sr][so] = *(const int4*)(vbase_p + (size_t)sr * SEQ + kb + so);
        __syncthreads();

        // scores: 16q x 64k strip
        f32x4 s[4];
        #pragma unroll
        for (int jn = 0; jn < 4; jn++) {
            f32x4 a = {0.f, 0.f, 0.f, 0.f};
            #pragma unroll
            for (int kc = 0; kc < 2; kc++) {
                bf16x8 kf = *(const bf16x8*)&Ks[jn * 16 + l15][kc * 32 + quad * 8];
                a = __builtin_amdgcn_mfma_f32_16x16x32_bf16(qf[kc], kf, a, 0, 0, 0);
            }
            int mv = mask[b * SEQ + kb + jn * 16 + l15];
            #pragma unroll
            for (int r = 0; r < 4; r++)
                a[r] = mv ? a[r] * (1.0f / 32.0f) : -1e9f;
            s[jn] = a;
        }
        // row max (local over jn, then across 16 cols in quad group)
        f32x4 mx = s[0];
        #pragma unroll
        for (int jn = 1; jn < 4; jn++)
            #pragma unroll
            for (int r = 0; r < 4; r++) mx[r] = fmaxf(mx[r], s[jn][r]);
        #pragma unroll
        for (int d = 1; d < 16; d <<= 1)
            #pragma unroll
            for (int r = 0; r < 4; r++)
                mx[r] = fmaxf(mx[r], __shfl_xor(mx[r], d, 16));

        // exact defer-max: if no row exceeds its running max, alpha == 1.
        bool nogrow = (mx[0] <= mrow[0]) && (mx[1] <= mrow[1]) &&
                      (mx[2] <= mrow[2]) && (mx[3] <= mrow[3]);
        if (!__all(nogrow)) {
            float alpha[4];
            #pragma unroll
            for (int r = 0; r < 4; r++) {
                float mnew = fmaxf(mrow[r], mx[r]);
                alpha[r] = __expf(mrow[r] - mnew);
                mrow[r] = mnew;
            }
            #pragma unroll
            for (int jd = 0; jd < 4; jd++)
                #pragma unroll
                for (int r = 0; r < 4; r++)
                    oacc[jd][r] *= alpha[r];
            #pragma unroll
            for (int r = 0; r < 4; r++)
                lrow[r] *= alpha[r];
        }

        // p = exp(s - mrow), row sums, write P to LDS
        f32x4 sum = {0.f, 0.f, 0.f, 0.f};
        #pragma unroll
        for (int jn = 0; jn < 4; jn++) {
            #pragma unroll
            for (int r = 0; r < 4; r++) {
                float p = __expf(s[jn][r] - mrow[r]);
                sum[r] += p;
                Ps[wq + quad * 4 + r][jn * 16 + l15] = f2bf(p);
            }
        }
        #pragma unroll
        for (int d = 1; d < 16; d <<= 1)
            #pragma unroll
            for (int r = 0; r < 4; r++)
                sum[r] += __shfl_xor(sum[r], d, 16);
        #pragma unroll
        for (int r = 0; r < 4; r++)
            lrow[r] += sum[r];

        __syncthreads();
        // O += P @ V
        #pragma unroll
        for (int jd = 0; jd < 4; jd++)
            #pragma unroll
            for (int kc = 0; kc < 2; kc++) {
                bf16x8 pf = *(const bf16x8*)&Ps[wq + l15][kc * 32 + quad * 8];
                bf16x8 vf = *(const bf16x8*)&Vt[jd * 16 + l15][kc * 32 + quad * 8];
                oacc[jd] = __builtin_amdgcn_mfma_f32_16x16x32_bf16(pf, vf, oacc[jd], 0, 0, 0);
            }
        __syncthreads();
    }

    // epilogue: O / l
    float inv[4];
    #pragma unroll
    for (int r = 0; r < 4; r++) inv[r] = 1.0f / lrow[r];
    #pragma unroll
    for (int jd = 0; jd < 4; jd++) {
        #pragma unroll
        for (int r = 0; r < 4; r++) {
            int row = b * SEQ + q0 + wq + quad * 4 + r;
            int col = h * DKH + jd * 16 + l15;
            out[(size_t)row * D_MODEL + col] = f2bf(oacc[jd][r] * inv[r]);
        }
    }
}

// -------------------- fused residual add + LayerNorm --------------------
__global__ __launch_bounds__(256) void add_ln(
        float* __restrict__ xf,
        const unsigned short* __restrict__ delta,
        const unsigned short* __restrict__ g,
        const unsigned short* __restrict__ be,
        unsigned short* __restrict__ xb)
{
    __shared__ float wsum[4], wsum2[4];
    int tok = blockIdx.x;
    int t = threadIdx.x;
    int d0 = t * 4;
    float4 xv = *(float4*)(xf + (size_t)tok * D_MODEL + d0);
    ushort4 dv = *(const ushort4*)(delta + (size_t)tok * D_MODEL + d0);
    float v0 = xv.x + bf2f(dv.x);
    float v1 = xv.y + bf2f(dv.y);
    float v2 = xv.z + bf2f(dv.z);
    float v3 = xv.w + bf2f(dv.w);
    float s = v0 + v1 + v2 + v3;
    float s2 = v0 * v0 + v1 * v1 + v2 * v2 + v3 * v3;
    #pragma unroll
    for (int off = 32; off > 0; off >>= 1) {
        s  += __shfl_down(s, off);
        s2 += __shfl_down(s2, off);
    }
    int wave = t >> 6, lane = t & 63;
    if (lane == 0) { wsum[wave] = s; wsum2[wave] = s2; }
    __syncthreads();
    float tot  = wsum[0] + wsum[1] + wsum[2] + wsum[3];
    float tot2 = wsum2[0] + wsum2[1] + wsum2[2] + wsum2[3];
    float mean = tot * (1.0f / 1024.0f);
    float var  = tot2 * (1.0f / 1024.0f) - mean * mean;
    float rs = rsqrtf(var + 1e-5f);
    ushort4 gv  = *(const ushort4*)(g + d0);
    ushort4 bev = *(const ushort4*)(be + d0);
    float y0 = (v0 - mean) * rs * bf2f(gv.x) + bf2f(bev.x);
    float y1 = (v1 - mean) * rs * bf2f(gv.y) + bf2f(bev.y);
    float y2 = (v2 - mean) * rs * bf2f(gv.z) + bf2f(bev.z);
    float y3 = (v3 - mean) * rs * bf2f(gv.w) + bf2f(bev.w);
    float4 yo = {y0, y1, y2, y3};
    *(float4*)(xf + (size_t)tok * D_MODEL + d0) = yo;
    ushort4 ob = {f2bf(y0), f2bf(y1), f2bf(y2), f2bf(y3)};
    *(ushort4*)(xb + (size_t)tok * D_MODEL + d0) = ob;
}

// -------------------- output store (dtype per flag) --------------------
__global__ __launch_bounds__(256) void copy_out_any(const float* __restrict__ xf,
        void* __restrict__ out, const int* __restrict__ flag)
{
    int i = blockIdx.x * 1024 + threadIdx.x * 4;
    float4 vv = *(const float4*)(xf + i);
    if (*flag) {
        *(float4*)((float*)out + i) = vv;
    } else {
        ushort4 o = {f2bf(vv.x), f2bf(vv.y), f2bf(vv.z), f2bf(vv.w)};
        *(ushort4*)((unsigned short*)out + i) = o;
    }
}

// -------------------- host side --------------------
extern "C" void kernel_launch(void* const* d_in, const int* in_sizes, int n_in,
                              void* d_out, int out_size, void* d_ws, size_t ws_size,
                              hipStream_t stream)
{
    const int* src  = (const int*)d_in[0];
    const int* mask = (const int*)d_in[1];
    const void* emb = d_in[2];
    const void* Wq  = d_in[3];
    const void* bq  = d_in[4];
    const void* Wk  = d_in[5];
    const void* bk  = d_in[6];
    const void* Wv  = d_in[7];
    const void* bv  = d_in[8];
    const void* Wo  = d_in[9];
    const void* bo  = d_in[10];
    const void* W1  = d_in[11];
    const void* b1  = d_in[12];
    const void* W2  = d_in[13];
    const void* b2  = d_in[14];
    const void* g1  = d_in[15];
    const void* be1 = d_in[16];
    const void* g2  = d_in[17];
    const void* be2 = d_in[18];

    char* wsb = (char*)d_ws;
    size_t off = 0;
    auto alloc = [&](size_t bytes) -> void* {
        void* p = wsb + off;
        off += (bytes + 255) & ~(size_t)255;
        return p;
    };
    float* xf           = (float*)alloc((size_t)NTOK * D_MODEL * 4);
    unsigned short* xb  = (unsigned short*)alloc((size_t)NTOK * D_MODEL * 2);
    unsigned short* qkv = (unsigned short*)alloc((size_t)NTOK * QKVN * 2);
    unsigned short* ao  = (unsigned short*)alloc((size_t)NTOK * D_MODEL * 2);
    unsigned short* ffb = (unsigned short*)alloc((size_t)NTOK * FFDIM * 2);
    unsigned short* wT  = (unsigned short*)alloc((size_t)D_MODEL * FFDIM * 2);
    unsigned short* arena = (unsigned short*)alloc(79872 * 2);
    int* flag           = (int*)alloc(256);
    unsigned short* tmp = qkv;   // qkv dead after attention; reuse for deltas
    unsigned short* vtb = ffb;   // ffb dead during attention; holds V^T [B,H,64,S]
    (void)ws_size; (void)in_sizes; (void)n_in; (void)out_size;

    const unsigned short* c_bqkv = arena;              // [L][3072]
    const unsigned short* c_bo  = arena + 18432;
    const unsigned short* c_b1  = arena + 24576;
    const unsigned short* c_b2  = arena + 49152;
    const unsigned short* c_g1  = arena + 55296;
    const unsigned short* c_be1 = arena + 61440;
    const unsigned short* c_g2  = arena + 67584;
    const unsigned short* c_be2 = arena + 73728;

    detect_dtype<<<1, 256, 0, stream>>>((const unsigned int*)emb, flag);
    cvt_params<<<312, 256, 0, stream>>>(bq, bk, bv, bo, b1, b2, g1, be1, g2, be2, arena, flag);
    embed_pe<<<NTOK, 256, 0, stream>>>(src, emb, xf, xb, flag);

    for (int l = 0; l < NLAYER; l++) {
        size_t offDD = (size_t)l * D_MODEL * D_MODEL;
        size_t offDF = (size_t)l * D_MODEL * FFDIM;

        // fused QKV: wT = [Wq^T | Wk^T | Wv^T] (3072 x 1024), one 768-block GEMM
        transpose_any<<<dim3(32, 32), 256, 0, stream>>>(Wq, offDD, wT,           D_MODEL, D_MODEL, flag);
        transpose_any<<<dim3(32, 32), 256, 0, stream>>>(Wk, offDD, wT + 1048576, D_MODEL, D_MODEL, flag);
        transpose_any<<<dim3(32, 32), 256, 0, stream>>>(Wv, offDD, wT + 2097152, D_MODEL, D_MODEL, flag);
        gemm_bt<0><<<dim3(32, 24), 256, 0, stream>>>(xb, wT, c_bqkv + (size_t)l * QKVN, qkv,
                                                     NTOK, QKVN, D_MODEL);

        transpose_v<<<dim3(SEQ / 32, D_MODEL / 32, BATCH), 256, 0, stream>>>(qkv, vtb);
        attn_mfma<<<dim3(SEQ / 128, NHEAD, BATCH), 512, 0, stream>>>(qkv, vtb, mask, ao);

        transpose_any<<<dim3(32, 32), 256, 0, stream>>>(Wo, offDD, wT, D_MODEL, D_MODEL, flag);
        gemm_bt<0><<<dim3(32, 8), 256, 0, stream>>>(ao, wT, c_bo + (size_t)l * D_MODEL, tmp,
                                                    NTOK, D_MODEL, D_MODEL);
        add_ln<<<NTOK, 256, 0, stream>>>(xf, tmp, c_g1 + (size_t)l * D_MODEL, c_be1 + (size_t)l * D_MODEL, xb);

        transpose_any<<<dim3(128, 32), 256, 0, stream>>>(W1, offDF, wT, D_MODEL, FFDIM, flag);
        gemm_bt<1><<<dim3(32, 32), 256, 0, stream>>>(xb, wT, c_b1 + (size_t)l * FFDIM, ffb,
                                                     NTOK, FFDIM, D_MODEL);
        transpose_any<<<dim3(32, 128), 256, 0, stream>>>(W2, offDF, wT, FFDIM, D_MODEL, flag);
        gemm_bt<0><<<dim3(32, 8), 256, 0, stream>>>(ffb, wT, c_b2 + (size_t)l * D_MODEL, tmp,
                                                    NTOK, D_MODEL, FFDIM);
        add_ln<<<NTOK, 256, 0, stream>>>(xf, tmp, c_g2 + (size_t)l * D_MODEL, c_be2 + (size_t)l * D_MODEL, xb);
    }

    copy_out_any<<<NTOK, 256, 0, stream>>>(xf, d_out, flag);
}

// Round 5
// 2554.038 us; speedup vs baseline: 1.1798x; 1.0305x over previous
//
#include <hip/hip_runtime.h>
#include <hip/hip_bf16.h>
#include <math.h>

// Problem constants
#define D_MODEL 1024
#define NHEAD   16
#define DKH     64
#define FFDIM   4096
#define NLAYER  6
#define BATCH   2
#define SEQ     2048
#define NTOK    (BATCH*SEQ)
#define QKVN    3072   // fused Q|K|V output width

typedef __bf16 bf16x8 __attribute__((ext_vector_type(8)));
typedef float  f32x4  __attribute__((ext_vector_type(4)));

static __device__ __forceinline__ float bf2f(unsigned short u) {
    union { unsigned int i; float f; } v; v.i = ((unsigned int)u) << 16; return v.f;
}
static __device__ __forceinline__ unsigned short f2bf(float f) {
    __hip_bfloat16 h = __float2bfloat16(f);
    return *reinterpret_cast<unsigned short*>(&h);
}

// async global->LDS, 16B per lane. LDS dest must be wave-uniform base;
// HW writes base + lane*16 (m104/m108). Global addr is per-lane.
static __device__ __forceinline__ void gld_lds16(const unsigned short* g, unsigned short* l)
{
    __builtin_amdgcn_global_load_lds(
        (const __attribute__((address_space(1))) void*)g,
        (__attribute__((address_space(3))) void*)l,
        16, 0, 0);
}

// -------------------- dtype detection --------------------
__global__ void detect_dtype(const unsigned int* __restrict__ p, int* __restrict__ flag)
{
    __shared__ int cnt;
    if (threadIdx.x == 0) cnt = 0;
    __syncthreads();
    int c = 0;
    for (int i = threadIdx.x; i < 1024; i += 256) {
        unsigned int e = (p[i] >> 7) & 0xFF;
        if (e >= 0x60 && e <= 0x90) c++;
    }
    atomicAdd(&cnt, c);
    __syncthreads();
    if (threadIdx.x == 0) *flag = (cnt < 512) ? 1 : 0;
}

// -------------------- bias/gain conversion into bf16 arena --------------------
// arena layout: [L][3072] fused qkv bias | bo [L][1024] | b1 [L][4096] | b2 | g1 | be1 | g2 | be2
__global__ __launch_bounds__(256) void cvt_params(
    const void* bq, const void* bk, const void* bv, const void* bo,
    const void* b1, const void* b2, const void* g1, const void* be1,
    const void* g2, const void* be2,
    unsigned short* __restrict__ arena, const int* __restrict__ flag)
{
    int i = blockIdx.x * 256 + threadIdx.x;
    if (i >= 79872) return;
    const void* src; int j;
    if (i < 18432) {
        int l = i / 3072, r = i - l * 3072;
        if (r < 1024)      { src = bq; j = l * 1024 + r; }
        else if (r < 2048) { src = bk; j = l * 1024 + r - 1024; }
        else               { src = bv; j = l * 1024 + r - 2048; }
    }
    else if (i < 24576) { src = bo;  j = i - 18432; }
    else if (i < 49152) { src = b1;  j = i - 24576; }
    else if (i < 55296) { src = b2;  j = i - 49152; }
    else if (i < 61440) { src = g1;  j = i - 55296; }
    else if (i < 67584) { src = be1; j = i - 61440; }
    else if (i < 73728) { src = g2;  j = i - 67584; }
    else                { src = be2; j = i - 73728; }
    arena[i] = (*flag) ? f2bf(((const float*)src)[j])
                       : ((const unsigned short*)src)[j];
}

// -------------------- embedding + positional encoding --------------------
__global__ __launch_bounds__(256) void embed_pe(const int* __restrict__ src,
        const void* __restrict__ emb,
        float* __restrict__ xf, unsigned short* __restrict__ xb,
        const int* __restrict__ flag)
{
    int tok = blockIdx.x;
    int b = tok / SEQ;
    int id = src[tok];
    int t = threadIdx.x;
    int d0 = t * 4;
    float ev[4];
    if (*flag) {
        float4 v = *(const float4*)((const float*)emb + (size_t)id * D_MODEL + d0);
        ev[0] = v.x; ev[1] = v.y; ev[2] = v.z; ev[3] = v.w;
    } else {
        ushort4 v = *(const ushort4*)((const unsigned short*)emb + (size_t)id * D_MODEL + d0);
        ev[0] = bf2f(v.x); ev[1] = bf2f(v.y); ev[2] = bf2f(v.z); ev[3] = bf2f(v.w);
    }
    float pos = (float)b;
    float vals[4];
    #pragma unroll
    for (int e = 0; e < 4; e++) {
        int d = d0 + e;
        int deven = d & ~1;
        float div_ = expf((float)deven * (-9.210340371976184f / 1024.0f));
        float ang = pos / div_;
        float pe = (d & 1) ? cosf(ang) : sinf(ang);
        vals[e] = ev[e] + pe;
    }
    float4 f4 = {vals[0], vals[1], vals[2], vals[3]};
    *(float4*)(xf + (size_t)tok * D_MODEL + d0) = f4;
    ushort4 o = {f2bf(vals[0]), f2bf(vals[1]), f2bf(vals[2]), f2bf(vals[3])};
    *(ushort4*)(xb + (size_t)tok * D_MODEL + d0) = o;
}

// -------------------- transpose (any dtype, +element offset) -> bf16 B^T ----
__global__ __launch_bounds__(256) void transpose_any(const void* __restrict__ in,
        size_t elemOff, unsigned short* __restrict__ out, int R, int Cn,
        const int* __restrict__ flag)
{
    __shared__ unsigned short tl[32][33];
    int isf = *flag;
    int c0 = blockIdx.x * 32, r0 = blockIdx.y * 32;
    int tc = threadIdx.x & 31, tr = threadIdx.x >> 5;
    #pragma unroll
    for (int i = 0; i < 4; i++) {
        int r = tr + i * 8;
        size_t idx = elemOff + (size_t)(r0 + r) * Cn + c0 + tc;
        tl[r][tc] = isf ? f2bf(((const float*)in)[idx])
                        : ((const unsigned short*)in)[idx];
    }
    __syncthreads();
    #pragma unroll
    for (int i = 0; i < 4; i++) {
        int r = tr + i * 8;
        out[(size_t)(c0 + r) * R + r0 + tc] = tl[tc][r];
    }
}

// -------------------- V transpose: qkv[:,2048:3072] -> vtb[B,H,64,S] --------
__global__ __launch_bounds__(256) void transpose_v(const unsigned short* __restrict__ qkv,
        unsigned short* __restrict__ vtb)
{
    __shared__ unsigned short tl[32][33];
    int s0 = blockIdx.x * 32, c0 = blockIdx.y * 32, b = blockIdx.z;
    int tc = threadIdx.x & 31, tr = threadIdx.x >> 5;
    #pragma unroll
    for (int i = 0; i < 4; i++) {
        int r = tr + i * 8;
        tl[r][tc] = qkv[(size_t)(b * SEQ + s0 + r) * QKVN + 2048 + c0 + tc];
    }
    __syncthreads();
    #pragma unroll
    for (int i = 0; i < 4; i++) {
        int r = tr + i * 8;        // r indexes d within this 32-col strip
        int dglob = c0 + r;
        int h = dglob >> 6, dd = dglob & 63;
        vtb[((size_t)(b * NHEAD + h) * DKH + dd) * SEQ + s0 + tc] = tl[tc][r];
    }
}

// -------------------- bf16 MFMA GEMM: C[M,N] = A[M,K] @ Bt^T + bias ---------
// m97 structure: linear LDS tiles, global_load_lds width=16 staging,
// double-buffered 2-phase (stage k+1 while computing k; one vmcnt-drain
// barrier per K-step -> latency hidden even at 1 block/CU).
template<int RELU>
__global__ __launch_bounds__(256) void gemm_bt(
        const unsigned short* __restrict__ A,
        const unsigned short* __restrict__ Bt,
        const unsigned short* __restrict__ bias,
        unsigned short* __restrict__ C,
        int M, int N, int K)
{
    __shared__ unsigned short As[2][128][32];
    __shared__ unsigned short Bs[2][128][32];
    int tid = threadIdx.x;
    int lane = tid & 63;
    int wave = tid >> 6;
    int bm = blockIdx.x * 128;
    int bn = blockIdx.y * 128;
    int wm = (wave >> 1) * 64;
    int wn = (wave & 1) * 64;
    int l15 = lane & 15;
    int quad = lane >> 4;

    f32x4 acc[4][4] = {};

    // staging: 8 chunks of 1024B per matrix tile; wave w owns chunks 2w,2w+1.
    // chunk ch covers rows [ch*16, ch*16+16); lane l -> row ch*16 + l/4, col (l&3)*8.
    int srow = lane >> 2;
    int scol = (lane & 3) * 8;
    int c0 = wave * 2, c1 = wave * 2 + 1;
    const unsigned short* Ag0 = A  + (size_t)(bm + c0 * 16 + srow) * K + scol;
    const unsigned short* Ag1 = A  + (size_t)(bm + c1 * 16 + srow) * K + scol;
    const unsigned short* Bg0 = Bt + (size_t)(bn + c0 * 16 + srow) * K + scol;
    const unsigned short* Bg1 = Bt + (size_t)(bn + c1 * 16 + srow) * K + scol;

#define GSTAGE(BUF, KOFF) do { \
    gld_lds16(Ag0 + (KOFF), &As[BUF][c0 * 16][0]); \
    gld_lds16(Ag1 + (KOFF), &As[BUF][c1 * 16][0]); \
    gld_lds16(Bg0 + (KOFF), &Bs[BUF][c0 * 16][0]); \
    gld_lds16(Bg1 + (KOFF), &Bs[BUF][c1 * 16][0]); \
} while (0)

#define GCOMPUTE(BUF) do { \
    bf16x8 af[4], bfr[4]; \
    _Pragma("unroll") \
    for (int i = 0; i < 4; i++) af[i] = *(const bf16x8*)&As[BUF][wm + i * 16 + l15][quad * 8]; \
    _Pragma("unroll") \
    for (int j = 0; j < 4; j++) bfr[j] = *(const bf16x8*)&Bs[BUF][wn + j * 16 + l15][quad * 8]; \
    _Pragma("unroll") \
    for (int i = 0; i < 4; i++) { \
        _Pragma("unroll") \
        for (int j = 0; j < 4; j++) \
            acc[i][j] = __builtin_amdgcn_mfma_f32_16x16x32_bf16(af[i], bfr[j], acc[i][j], 0, 0, 0); \
    } \
} while (0)

    GSTAGE(0, 0);
    __syncthreads();              // compiler emits vmcnt(0) drain before barrier
    int cur = 0;
    for (int k0 = 32; k0 < K; k0 += 32) {
        GSTAGE(cur ^ 1, k0);      // async prefetch of next tile, in flight during compute
        GCOMPUTE(cur);
        __syncthreads();          // drains prefetch + guards buffer reuse
        cur ^= 1;
    }
    GCOMPUTE(cur);

#undef GSTAGE
#undef GCOMPUTE

    #pragma unroll
    for (int i = 0; i < 4; i++) {
        int row0 = bm + wm + i * 16 + quad * 4;
        #pragma unroll
        for (int j = 0; j < 4; j++) {
            int col = bn + wn + j * 16 + l15;
            float bv = bf2f(bias[col]);
            #pragma unroll
            for (int r = 0; r < 4; r++) {
                float v = acc[i][j][r] + bv;
                if (RELU) v = fmaxf(v, 0.0f);
                C[(size_t)(row0 + r) * N + col] = f2bf(v);
            }
        }
    }
}

// -------------------- MFMA flash attention --------------------
// Block: 512 thr (8 waves), Q-tile 128 (16 q/wave), K-tile 64, head dim 64.
// Single barrier per K-tile: Ks/Vt double-buffered in LDS; next tile's K/V
// prefetched global->reg BEFORE compute (T14 async-stage: vmcnt drain lands
// after the tile's MFMA/softmax work), reg->LDS written into buf^1 after
// compute. Mid softmax->PV barrier removed: Ps rows are wave-private
// (wave w writes AND reads only rows [16w,16w+16)). setprio(1) around MFMA
// clusters (T5; pays now that waves run desynchronized).
// q/k read from fused qkv buffer (row stride 3072, k at +1024).
// Exact defer-max: alpha==1 when no row's tile-max exceeds running max.
// scale = 1/sqrt(D_MODEL) = 1/32 (reference quirk).
__global__ __launch_bounds__(512) void attn_mfma(
        const unsigned short* __restrict__ qkv,
        const unsigned short* __restrict__ vtb,   // [B,H,64,SEQ]
        const int* __restrict__ mask,
        unsigned short* __restrict__ out)
{
    __shared__ unsigned short Ks[2][64][72];
    __shared__ unsigned short Vt[2][64][72];
    __shared__ unsigned short Ps[128][72];

    int qt = blockIdx.x, h = blockIdx.y, b = blockIdx.z;
    int t = threadIdx.x, lane = t & 63, wave = t >> 6;   // 8 waves
    int l15 = lane & 15, quad = lane >> 4;
    int q0 = qt * 128;
    int wq = wave * 16;                                   // 16 q rows per wave

    const unsigned short* qbase   = qkv + (size_t)b * SEQ * QKVN + h * DKH;
    const unsigned short* kbase_p = qkv + (size_t)b * SEQ * QKVN + 1024 + h * DKH;
    const unsigned short* vbase_p = vtb + (size_t)(b * NHEAD + h) * DKH * SEQ;

    // Q fragments: 2 k-chunks, resident all kernel
    bf16x8 qf[2];
    #pragma unroll
    for (int kc = 0; kc < 2; kc++)
        qf[kc] = *(const bf16x8*)(qbase +
            (size_t)(q0 + wq + l15) * QKVN + kc * 32 + quad * 8);

    f32x4 oacc[4] = {};
    float mrow[4], lrow[4];
    #pragma unroll
    for (int r = 0; r < 4; r++) { mrow[r] = -INFINITY; lrow[r] = 0.0f; }

    // staging coords: 512 threads, one int4 each per matrix; row=t/8, col=(t%8)*8
    int sr = t >> 3, so = (t & 7) * 8;

    // prologue: tile 0 -> regs -> buf0
    int4 kreg = *(const int4*)(kbase_p + (size_t)sr * QKVN + so);
    int4 vreg = *(const int4*)(vbase_p + (size_t)sr * SEQ + so);
    *(int4*)&Ks[0][sr][so] = kreg;
    *(int4*)&Vt[0][sr][so] = vreg;
    __syncthreads();

    int cur = 0;
    for (int kb = 0; kb < SEQ; kb += 64) {
        int nkb = kb + 64;
        // issue next-tile prefetch (in flight across the whole compute phase)
        if (nkb < SEQ) {
            kreg = *(const int4*)(kbase_p + (size_t)(nkb + sr) * QKVN + so);
            vreg = *(const int4*)(vbase_p + (size_t)sr * SEQ + nkb + so);
        }

        // scores: 16q x 64k strip
        f32x4 s[4];
        __builtin_amdgcn_s_setprio(1);
        #pragma unroll
        for (int jn = 0; jn < 4; jn++) {
            f32x4 a = {0.f, 0.f, 0.f, 0.f};
            #pragma unroll
            for (int kc = 0; kc < 2; kc++) {
                bf16x8 kf = *(const bf16x8*)&Ks[cur][jn * 16 + l15][kc * 32 + quad * 8];
                a = __builtin_amdgcn_mfma_f32_16x16x32_bf16(qf[kc], kf, a, 0, 0, 0);
            }
            s[jn] = a;
        }
        __builtin_amdgcn_s_setprio(0);
        #pragma unroll
        for (int jn = 0; jn < 4; jn++) {
            int mv = mask[b * SEQ + kb + jn * 16 + l15];
            #pragma unroll
            for (int r = 0; r < 4; r++)
                s[jn][r] = mv ? s[jn][r] * (1.0f / 32.0f) : -1e9f;
        }
        // row max (local over jn, then across 16 cols in quad group)
        f32x4 mx = s[0];
        #pragma unroll
        for (int jn = 1; jn < 4; jn++)
            #pragma unroll
            for (int r = 0; r < 4; r++) mx[r] = fmaxf(mx[r], s[jn][r]);
        #pragma unroll
        for (int d = 1; d < 16; d <<= 1)
            #pragma unroll
            for (int r = 0; r < 4; r++)
                mx[r] = fmaxf(mx[r], __shfl_xor(mx[r], d, 16));

        // exact defer-max: if no row exceeds its running max, alpha == 1.
        bool nogrow = (mx[0] <= mrow[0]) && (mx[1] <= mrow[1]) &&
                      (mx[2] <= mrow[2]) && (mx[3] <= mrow[3]);
        if (!__all(nogrow)) {
            float alpha[4];
            #pragma unroll
            for (int r = 0; r < 4; r++) {
                float mnew = fmaxf(mrow[r], mx[r]);
                alpha[r] = __expf(mrow[r] - mnew);
                mrow[r] = mnew;
            }
            #pragma unroll
            for (int jd = 0; jd < 4; jd++)
                #pragma unroll
                for (int r = 0; r < 4; r++)
                    oacc[jd][r] *= alpha[r];
            #pragma unroll
            for (int r = 0; r < 4; r++)
                lrow[r] *= alpha[r];
        }

        // p = exp(s - mrow), row sums, write P to LDS (wave-private rows)
        f32x4 sum = {0.f, 0.f, 0.f, 0.f};
        #pragma unroll
        for (int jn = 0; jn < 4; jn++) {
            #pragma unroll
            for (int r = 0; r < 4; r++) {
                float p = __expf(s[jn][r] - mrow[r]);
                sum[r] += p;
                Ps[wq + quad * 4 + r][jn * 16 + l15] = f2bf(p);
            }
        }
        #pragma unroll
        for (int d = 1; d < 16; d <<= 1)
            #pragma unroll
            for (int r = 0; r < 4; r++)
                sum[r] += __shfl_xor(sum[r], d, 16);
        #pragma unroll
        for (int r = 0; r < 4; r++)
            lrow[r] += sum[r];

        // O += P @ V  (no barrier needed: Ps rows wave-private, Ks/Vt read-only)
        __builtin_amdgcn_s_setprio(1);
        #pragma unroll
        for (int jd = 0; jd < 4; jd++)
            #pragma unroll
            for (int kc = 0; kc < 2; kc++) {
                bf16x8 pf = *(const bf16x8*)&Ps[wq + l15][kc * 32 + quad * 8];
                bf16x8 vf = *(const bf16x8*)&Vt[cur][jd * 16 + l15][kc * 32 + quad * 8];
                oacc[jd] = __builtin_amdgcn_mfma_f32_16x16x32_bf16(pf, vf, oacc[jd], 0, 0, 0);
            }
        __builtin_amdgcn_s_setprio(0);

        // write prefetched tile into the other buffer (safe: buf^1 last read
        // before the previous barrier), then single barrier
        if (nkb < SEQ) {
            *(int4*)&Ks[cur ^ 1][sr][so] = kreg;
            *(int4*)&Vt[cur ^ 1][sr][so] = vreg;
        }
        __syncthreads();
        cur ^= 1;
    }

    // epilogue: O / l
    float inv[4];
    #pragma unroll
    for (int r = 0; r < 4; r++) inv[r] = 1.0f / lrow[r];
    #pragma unroll
    for (int jd = 0; jd < 4; jd++) {
        #pragma unroll
        for (int r = 0; r < 4; r++) {
            int row = b * SEQ + q0 + wq + quad * 4 + r;
            int col = h * DKH + jd * 16 + l15;
            out[(size_t)row * D_MODEL + col] = f2bf(oacc[jd][r] * inv[r]);
        }
    }
}

// -------------------- fused residual add + LayerNorm --------------------
__global__ __launch_bounds__(256) void add_ln(
        float* __restrict__ xf,
        const unsigned short* __restrict__ delta,
        const unsigned short* __restrict__ g,
        const unsigned short* __restrict__ be,
        unsigned short* __restrict__ xb)
{
    __shared__ float wsum[4], wsum2[4];
    int tok = blockIdx.x;
    int t = threadIdx.x;
    int d0 = t * 4;
    float4 xv = *(float4*)(xf + (size_t)tok * D_MODEL + d0);
    ushort4 dv = *(const ushort4*)(delta + (size_t)tok * D_MODEL + d0);
    float v0 = xv.x + bf2f(dv.x);
    float v1 = xv.y + bf2f(dv.y);
    float v2 = xv.z + bf2f(dv.z);
    float v3 = xv.w + bf2f(dv.w);
    float s = v0 + v1 + v2 + v3;
    float s2 = v0 * v0 + v1 * v1 + v2 * v2 + v3 * v3;
    #pragma unroll
    for (int off = 32; off > 0; off >>= 1) {
        s  += __shfl_down(s, off);
        s2 += __shfl_down(s2, off);
    }
    int wave = t >> 6, lane = t & 63;
    if (lane == 0) { wsum[wave] = s; wsum2[wave] = s2; }
    __syncthreads();
    float tot  = wsum[0] + wsum[1] + wsum[2] + wsum[3];
    float tot2 = wsum2[0] + wsum2[1] + wsum2[2] + wsum2[3];
    float mean = tot * (1.0f / 1024.0f);
    float var  = tot2 * (1.0f / 1024.0f) - mean * mean;
    float rs = rsqrtf(var + 1e-5f);
    ushort4 gv  = *(const ushort4*)(g + d0);
    ushort4 bev = *(const ushort4*)(be + d0);
    float y0 = (v0 - mean) * rs * bf2f(gv.x) + bf2f(bev.x);
    float y1 = (v1 - mean) * rs * bf2f(gv.y) + bf2f(bev.y);
    float y2 = (v2 - mean) * rs * bf2f(gv.z) + bf2f(bev.z);
    float y3 = (v3 - mean) * rs * bf2f(gv.w) + bf2f(bev.w);
    float4 yo = {y0, y1, y2, y3};
    *(float4*)(xf + (size_t)tok * D_MODEL + d0) = yo;
    ushort4 ob = {f2bf(y0), f2bf(y1), f2bf(y2), f2bf(y3)};
    *(ushort4*)(xb + (size_t)tok * D_MODEL + d0) = ob;
}

// -------------------- output store (dtype per flag) --------------------
__global__ __launch_bounds__(256) void copy_out_any(const float* __restrict__ xf,
        void* __restrict__ out, const int* __restrict__ flag)
{
    int i = blockIdx.x * 1024 + threadIdx.x * 4;
    float4 vv = *(const float4*)(xf + i);
    if (*flag) {
        *(float4*)((float*)out + i) = vv;
    } else {
        ushort4 o = {f2bf(vv.x), f2bf(vv.y), f2bf(vv.z), f2bf(vv.w)};
        *(ushort4*)((unsigned short*)out + i) = o;
    }
}

// -------------------- host side --------------------
extern "C" void kernel_launch(void* const* d_in, const int* in_sizes, int n_in,
                              void* d_out, int out_size, void* d_ws, size_t ws_size,
                              hipStream_t stream)
{
    const int* src  = (const int*)d_in[0];
    const int* mask = (const int*)d_in[1];
    const void* emb = d_in[2];
    const void* Wq  = d_in[3];
    const void* bq  = d_in[4];
    const void* Wk  = d_in[5];
    const void* bk  = d_in[6];
    const void* Wv  = d_in[7];
    const void* bv  = d_in[8];
    const void* Wo  = d_in[9];
    const void* bo  = d_in[10];
    const void* W1  = d_in[11];
    const void* b1  = d_in[12];
    const void* W2  = d_in[13];
    const void* b2  = d_in[14];
    const void* g1  = d_in[15];
    const void* be1 = d_in[16];
    const void* g2  = d_in[17];
    const void* be2 = d_in[18];

    char* wsb = (char*)d_ws;
    size_t off = 0;
    auto alloc = [&](size_t bytes) -> void* {
        void* p = wsb + off;
        off += (bytes + 255) & ~(size_t)255;
        return p;
    };
    float* xf           = (float*)alloc((size_t)NTOK * D_MODEL * 4);
    unsigned short* xb  = (unsigned short*)alloc((size_t)NTOK * D_MODEL * 2);
    unsigned short* qkv = (unsigned short*)alloc((size_t)NTOK * QKVN * 2);
    unsigned short* ao  = (unsigned short*)alloc((size_t)NTOK * D_MODEL * 2);
    unsigned short* ffb = (unsigned short*)alloc((size_t)NTOK * FFDIM * 2);
    unsigned short* wT  = (unsigned short*)alloc((size_t)D_MODEL * FFDIM * 2);
    unsigned short* arena = (unsigned short*)alloc(79872 * 2);
    int* flag           = (int*)alloc(256);
    unsigned short* tmp = qkv;   // qkv dead after attention; reuse for deltas
    unsigned short* vtb = ffb;   // ffb dead during attention; holds V^T [B,H,64,S]
    (void)ws_size; (void)in_sizes; (void)n_in; (void)out_size;

    const unsigned short* c_bqkv = arena;              // [L][3072]
    const unsigned short* c_bo  = arena + 18432;
    const unsigned short* c_b1  = arena + 24576;
    const unsigned short* c_b2  = arena + 49152;
    const unsigned short* c_g1  = arena + 55296;
    const unsigned short* c_be1 = arena + 61440;
    const unsigned short* c_g2  = arena + 67584;
    const unsigned short* c_be2 = arena + 73728;

    detect_dtype<<<1, 256, 0, stream>>>((const unsigned int*)emb, flag);
    cvt_params<<<312, 256, 0, stream>>>(bq, bk, bv, bo, b1, b2, g1, be1, g2, be2, arena, flag);
    embed_pe<<<NTOK, 256, 0, stream>>>(src, emb, xf, xb, flag);

    for (int l = 0; l < NLAYER; l++) {
        size_t offDD = (size_t)l * D_MODEL * D_MODEL;
        size_t offDF = (size_t)l * D_MODEL * FFDIM;

        // fused QKV: wT = [Wq^T | Wk^T | Wv^T] (3072 x 1024), one 768-block GEMM
        transpose_any<<<dim3(32, 32), 256, 0, stream>>>(Wq, offDD, wT,           D_MODEL, D_MODEL, flag);
        transpose_any<<<dim3(32, 32), 256, 0, stream>>>(Wk, offDD, wT + 1048576, D_MODEL, D_MODEL, flag);
        transpose_any<<<dim3(32, 32), 256, 0, stream>>>(Wv, offDD, wT + 2097152, D_MODEL, D_MODEL, flag);
        gemm_bt<0><<<dim3(32, 24), 256, 0, stream>>>(xb, wT, c_bqkv + (size_t)l * QKVN, qkv,
                                                     NTOK, QKVN, D_MODEL);

        transpose_v<<<dim3(SEQ / 32, D_MODEL / 32, BATCH), 256, 0, stream>>>(qkv, vtb);
        attn_mfma<<<dim3(SEQ / 128, NHEAD, BATCH), 512, 0, stream>>>(qkv, vtb, mask, ao);

        transpose_any<<<dim3(32, 32), 256, 0, stream>>>(Wo, offDD, wT, D_MODEL, D_MODEL, flag);
        gemm_bt<0><<<dim3(32, 8), 256, 0, stream>>>(ao, wT, c_bo + (size_t)l * D_MODEL, tmp,
                                                    NTOK, D_MODEL, D_MODEL);
        add_ln<<<NTOK, 256, 0, stream>>>(xf, tmp, c_g1 + (size_t)l * D_MODEL, c_be1 + (size_t)l * D_MODEL, xb);

        transpose_any<<<dim3(128, 32), 256, 0, stream>>>(W1, offDF, wT, D_MODEL, FFDIM, flag);
        gemm_bt<1><<<dim3(32, 32), 256, 0, stream>>>(xb, wT, c_b1 + (size_t)l * FFDIM, ffb,
                                                     NTOK, FFDIM, D_MODEL);
        transpose_any<<<dim3(32, 128), 256, 0, stream>>>(W2, offDF, wT, FFDIM, D_MODEL, flag);
        gemm_bt<0><<<dim3(32, 8), 256, 0, stream>>>(ffb, wT, c_b2 + (size_t)l * D_MODEL, tmp,
                                                    NTOK, D_MODEL, FFDIM);
        add_ln<<<NTOK, 256, 0, stream>>>(xf, tmp, c_g2 + (size_t)l * D_MODEL, c_be2 + (size_t)l * D_MODEL, xb);
    }

    copy_out_any<<<NTOK, 256, 0, stream>>>(xf, d_out, flag);
}